// Round 1
// 387.082 us; speedup vs baseline: 1.2419x; 1.2419x over previous
//
#include <hip/hip_runtime.h>

#define N_FEAT0 128
#define HID 64
#define NCLS 40

#define BSH 9            // log2 nodes per bucket
#define BSZ 512          // nodes per bucket
#define BCAP 12288       // slab capacity per bucket (mean 8192, sigma ~90 -> 45 sigma margin)
#define STILE 16384      // edges per scatter block

// ---------------- phase 1: LDS-binned scatter of edges into per-bucket slabs ----
// Record = (d & 511) << 17 | s   (s < 2^17 since N = 100000 < 131072).
// Per block: histogram 196 buckets in LDS, reserve contiguous sub-ranges with ONE
// global atomic per bucket, then write ~84 contiguous records per bucket ->
// full-line writebacks instead of 1 line per 8B record (102MB -> ~10MB writes).
__global__ __launch_bounds__(256) void scatter_kernel(const int* __restrict__ esrc,
                                                      const int* __restrict__ edst,
                                                      int* __restrict__ bfill,
                                                      int* __restrict__ slab, int E) {
  __shared__ int cnt[256];
  __shared__ int base[256];
  int t = threadIdx.x;
  int t0 = blockIdx.x * STILE;
  cnt[t] = 0;
  __syncthreads();

  // pass A: histogram
#pragma unroll 4
  for (int i = 0; i < STILE / 1024; ++i) {
    int e = t0 + i * 1024 + t * 4;
    if (e < E) {
      int4 d4 = *(const int4*)(edst + e);
      atomicAdd(&cnt[d4.x >> BSH], 1);
      atomicAdd(&cnt[d4.y >> BSH], 1);
      atomicAdd(&cnt[d4.z >> BSH], 1);
      atomicAdd(&cnt[d4.w >> BSH], 1);
    }
  }
  __syncthreads();
  int c = cnt[t];
  if (c > 0) base[t] = t * BCAP + atomicAdd(&bfill[t], c);
  cnt[t] = 0;
  __syncthreads();

  // pass B: binned write (tile is L2-warm from pass A)
#pragma unroll 4
  for (int i = 0; i < STILE / 1024; ++i) {
    int e = t0 + i * 1024 + t * 4;
    if (e < E) {
      int4 s4 = *(const int4*)(esrc + e);
      int4 d4 = *(const int4*)(edst + e);
#define EMIT(dd, ss)                                             \
      {                                                          \
        int b_ = (dd) >> BSH;                                    \
        int r_ = atomicAdd(&cnt[b_], 1);                         \
        slab[base[b_] + r_] = (((dd) & (BSZ - 1)) << 17) | (ss); \
      }
      EMIT(d4.x, s4.x)
      EMIT(d4.y, s4.y)
      EMIT(d4.z, s4.z)
      EMIT(d4.w, s4.w)
#undef EMIT
    }
  }
}

// ---------------- scan of bucket sizes -> bucket bases ----------------
__global__ __launch_bounds__(256) void bscan_kernel(const int* __restrict__ bfill,
                                                    int* __restrict__ bbase,
                                                    int* __restrict__ row_ptr,
                                                    int nbuck, int N) {
  __shared__ int sh[256];
  int t = threadIdx.x;
  int v = (t < nbuck) ? bfill[t] : 0;
  sh[t] = v;
  __syncthreads();
  for (int off = 1; off < 256; off <<= 1) {
    int u = (t >= off) ? sh[t - off] : 0;
    __syncthreads();
    sh[t] += u;
    __syncthreads();
  }
  if (t < nbuck) bbase[t] = sh[t] - v;  // exclusive
  if (t == 255) {
    bbase[nbuck] = sh[255];
    row_ptr[N] = sh[255];  // == E
  }
}

// ---------------- phase 2: per-bucket CSR finalize ----------------
// One block per bucket: per-node histogram + prefix in LDS gives row_ptr and
// dinv directly (replaces count_kernel + 3 scan kernels), then permutes the
// slab into final node order. Scatter window <= ~48KB -> L2-absorbed writes.
__global__ __launch_bounds__(256) void build_kernel(const int* __restrict__ slab,
                                                    const int* __restrict__ bfill,
                                                    const int* __restrict__ bbase,
                                                    int* __restrict__ row_ptr,
                                                    float* __restrict__ dinv,
                                                    int* __restrict__ ew, int N) {
  __shared__ int cnt[512];
  __shared__ int pre[512];
  __shared__ int s2[256];
  int b = blockIdx.x;
  int t = threadIdx.x;
  int nbase = b << BSH;
  int nNodes = N - nbase;
  if (nNodes > BSZ) nNodes = BSZ;
  cnt[t] = 0;
  cnt[t + 256] = 0;
  __syncthreads();

  int sz = bfill[b];
  int sbeg = b * BCAP;
  int obase = bbase[b];

  // per-node histogram
  for (int r = t; r < sz; r += 256) atomicAdd(&cnt[((unsigned)slab[sbeg + r]) >> 17], 1);
  __syncthreads();

  // exclusive prefix over 512 counters (pair-sum + 256-wide scan)
  int a = cnt[2 * t], c = cnt[2 * t + 1];
  s2[t] = a + c;
  __syncthreads();
  for (int off = 1; off < 256; off <<= 1) {
    int u = (t >= off) ? s2[t - off] : 0;
    __syncthreads();
    s2[t] += u;
    __syncthreads();
  }
  int ex = s2[t] - (a + c);
  pre[2 * t] = ex;
  pre[2 * t + 1] = ex + a;
  __syncthreads();

  // row_ptr + dinv (coalesced)
  if (t < nNodes) {
    row_ptr[nbase + t] = obase + pre[t];
    dinv[nbase + t] = rsqrtf((float)(cnt[t] + 1));
  }
  int t2 = t + 256;
  if (t2 < nNodes) {
    row_ptr[nbase + t2] = obase + pre[t2];
    dinv[nbase + t2] = rsqrtf((float)(cnt[t2] + 1));
  }
  __syncthreads();
  cnt[t] = 0;
  cnt[t + 256] = 0;
  __syncthreads();

  // final permute: slab (coalesced read, L2-warm) -> node-ordered ew
  for (int r = t; r < sz; r += 256) {
    int rec = slab[sbeg + r];
    int dloc = ((unsigned)rec) >> 17;
    int rank = atomicAdd(&cnt[dloc], 1);
    ew[obase + pre[dloc] + rank] = rec & 0x1FFFF;  // src only; weight folded out
  }
}

// ---------------- dense GEMM with dinv row-scale epilogue ----------------
// Out[r][c] = dinv[r] * sum_k A[r][k] W[k][c]  (g = dinv (.) (h@W) factoring:
// out[d] = relu(dinv_d * (sum g_s + g_d)) -> edge records need no weight).
template <int K, int NC>
__global__ __launch_bounds__(256) void gemm_kernel(const float* __restrict__ A,
                                                   const float* __restrict__ W,
                                                   float* __restrict__ Out,
                                                   const float* __restrict__ rowscale,
                                                   int N) {
  constexpr int BK = 64;
  constexpr int LDSS = 68;           // LDS row stride in floats (17 x float4)
  __shared__ float As[128 * LDSS];   // 34816 B

  int t = threadIdx.x;
  int lane = t & 63;
  int wave = t >> 6;
  int c4 = lane & 15;                // col-quad 0..15
  int qr = lane >> 4;                // row phase 0..3
  int r0 = blockIdx.x * 128;

  int wc = 4 * c4;                   // W col base, clamped in-bounds for NC=40
  if (wc > NC - 4) wc = NC - 4;
  bool cok = (wc == 4 * c4);         // lanes whose cols are real (all for NC=64)

  float4 acc[8];
#pragma unroll
  for (int m = 0; m < 8; ++m) acc[m] = make_float4(0.f, 0.f, 0.f, 0.f);

  for (int kc = 0; kc < K; kc += BK) {
    __syncthreads();  // protect previous chunk's reads
#pragma unroll
    for (int i = 0; i < 8; ++i) {
      int idx = t + i * 256;         // 0..2047
      int row = idx >> 4;            // 0..127
      int cq = idx & 15;
      int gr = r0 + row;
      if (gr >= N) gr = N - 1;
      float4 v = *(const float4*)(A + (size_t)gr * K + kc + 4 * cq);
      *(float4*)(As + row * LDSS + 4 * cq) = v;
    }
    __syncthreads();

#pragma unroll 2
    for (int kk = 0; kk < BK / 4; ++kk) {
      float4 w[4];
#pragma unroll
      for (int k = 0; k < 4; ++k)
        w[k] = *(const float4*)(W + (size_t)(kc + kk * 4 + k) * NC + wc);
#pragma unroll
      for (int m = 0; m < 8; ++m) {
        int lrow = wave * 32 + qr + 4 * m;
        float4 a = *(const float4*)(As + lrow * LDSS + kk * 4);
        acc[m].x = fmaf(a.x, w[0].x, acc[m].x);
        acc[m].y = fmaf(a.x, w[0].y, acc[m].y);
        acc[m].z = fmaf(a.x, w[0].z, acc[m].z);
        acc[m].w = fmaf(a.x, w[0].w, acc[m].w);
        acc[m].x = fmaf(a.y, w[1].x, acc[m].x);
        acc[m].y = fmaf(a.y, w[1].y, acc[m].y);
        acc[m].z = fmaf(a.y, w[1].z, acc[m].z);
        acc[m].w = fmaf(a.y, w[1].w, acc[m].w);
        acc[m].x = fmaf(a.z, w[2].x, acc[m].x);
        acc[m].y = fmaf(a.z, w[2].y, acc[m].y);
        acc[m].z = fmaf(a.z, w[2].z, acc[m].z);
        acc[m].w = fmaf(a.z, w[2].w, acc[m].w);
        acc[m].x = fmaf(a.w, w[3].x, acc[m].x);
        acc[m].y = fmaf(a.w, w[3].y, acc[m].y);
        acc[m].z = fmaf(a.w, w[3].z, acc[m].z);
        acc[m].w = fmaf(a.w, w[3].w, acc[m].w);
      }
    }
  }

  if (cok) {
#pragma unroll
    for (int m = 0; m < 8; ++m) {
      int gr = r0 + wave * 32 + qr + 4 * m;
      if (gr < N) {
        float ds = rowscale[gr];
        acc[m].x *= ds; acc[m].y *= ds; acc[m].z *= ds; acc[m].w *= ds;
        *(float4*)(Out + (size_t)gr * NC + wc) = acc[m];
      }
    }
  }
}

// ---------------- sparse aggregation: one wave per node, lane = feature ----------------
// Unit edge weights (dinv folded into gemm epilogue + final dinv[v] scale).
template <int F>
__global__ __launch_bounds__(256) void agg_kernel(const float* __restrict__ Hin,
                                                  const int* __restrict__ row_ptr,
                                                  const int* __restrict__ ew,
                                                  const float* __restrict__ dinv,
                                                  float* __restrict__ Hout, int N) {
  int gid = blockIdx.x * blockDim.x + threadIdx.x;
  int v = gid >> 6;
  int lane = threadIdx.x & 63;
  if (v >= N) return;
  int f = (lane < F) ? lane : 0;
  float acc0 = Hin[(size_t)v * F + f];  // self-loop term (g_v)
  float acc1 = 0.f, acc2 = 0.f, acc3 = 0.f;
  int beg = __builtin_amdgcn_readfirstlane(row_ptr[v]);
  int end = __builtin_amdgcn_readfirstlane(row_ptr[v + 1]);
  int j = beg;
  for (; j + 3 < end; j += 4) {
    int s0 = ew[j];
    int s1 = ew[j + 1];
    int s2 = ew[j + 2];
    int s3 = ew[j + 3];
    acc0 += Hin[(size_t)s0 * F + f];
    acc1 += Hin[(size_t)s1 * F + f];
    acc2 += Hin[(size_t)s2 * F + f];
    acc3 += Hin[(size_t)s3 * F + f];
  }
  for (; j < end; ++j) {
    int s0 = ew[j];
    acc0 += Hin[(size_t)s0 * F + f];
  }
  if (lane < F)
    Hout[(size_t)v * F + lane] = fmaxf(dinv[v] * ((acc0 + acc1) + (acc2 + acc3)), 0.f);
}

extern "C" void kernel_launch(void* const* d_in, const int* in_sizes, int n_in,
                              void* d_out, int out_size, void* d_ws, size_t ws_size,
                              hipStream_t stream) {
  const float* x  = (const float*)d_in[0];
  const int*   eg = (const int*)d_in[1];
  const float* W0 = (const float*)d_in[2];
  const float* W1 = (const float*)d_in[3];
  const float* W2 = (const float*)d_in[4];
  float* out = (float*)d_out;

  const int N = in_sizes[0] / N_FEAT0;  // 100000
  const int E = in_sizes[1] / 2;        // 1600000
  const int* esrc = eg;
  const int* edst = eg + E;
  const int nbuck = (N + BSZ - 1) >> BSH;  // 196

  // workspace layout (256B aligned)
  char* p = (char*)d_ws;
  auto alloc = [&](size_t bytes) {
    char* r = p;
    p += (bytes + 255) & ~(size_t)255;
    return r;
  };
  int*   bfill   = (int*)alloc(256 * 4);
  int*   bbase   = (int*)alloc(260 * 4);
  int*   row_ptr = (int*)alloc((size_t)(N + 1) * 4);
  float* dinv    = (float*)alloc((size_t)N * 4);
  int*   ew      = (int*)alloc((size_t)E * 4);
  float* bufA    = (float*)alloc((size_t)N * HID * 4);
  float* bufB    = (float*)alloc((size_t)N * HID * 4);
  // per-bucket slab aliases bufA (nbuck*BCAP*4 = 9.6MB <= 25.6MB); build reads
  // it before gemm0 writes bufA (stream-ordered).
  int* slab = (int*)bufA;

  hipMemsetAsync(bfill, 0, 256 * 4, stream);

  const int sblocks = (E + STILE - 1) / STILE;  // 98
  scatter_kernel<<<sblocks, 256, 0, stream>>>(esrc, edst, bfill, slab, E);
  bscan_kernel<<<1, 256, 0, stream>>>(bfill, bbase, row_ptr, nbuck, N);
  build_kernel<<<nbuck, 256, 0, stream>>>(slab, bfill, bbase, row_ptr, dinv, ew, N);

  const int gblocks = (N + 127) / 128;
  const int ablocks = (N + 3) / 4;
  // layer 0: 128 -> 64
  gemm_kernel<128, 64><<<gblocks, 256, 0, stream>>>(x, W0, bufA, dinv, N);
  agg_kernel<64><<<ablocks, 256, 0, stream>>>(bufA, row_ptr, ew, dinv, bufB, N);
  // layer 1: 64 -> 64
  gemm_kernel<64, 64><<<gblocks, 256, 0, stream>>>(bufB, W1, bufA, dinv, N);
  agg_kernel<64><<<ablocks, 256, 0, stream>>>(bufA, row_ptr, ew, dinv, bufB, N);
  // layer 2: 64 -> 40
  gemm_kernel<64, 40><<<gblocks, 256, 0, stream>>>(bufB, W2, bufA, dinv, N);
  agg_kernel<40><<<ablocks, 256, 0, stream>>>(bufA, row_ptr, ew, dinv, out, N);
}

// Round 2
// 384.348 us; speedup vs baseline: 1.2507x; 1.0071x over previous
//
#include <hip/hip_runtime.h>

#define N_FEAT0 128
#define HID 64
#define NCLS 40

#define BSH 9            // log2 nodes per bucket
#define BSZ 512          // nodes per bucket
#define BCAP 12288       // slab capacity per bucket (mean 8192, sigma ~90 -> 45 sigma margin)
#define STILE 16384      // edges per scatter block

// ---------------- phase 1: LDS-binned scatter of edges into per-bucket slabs ----
// Record = (d & 511) << 17 | s   (s < 2^17 since N = 100000 < 131072).
__global__ __launch_bounds__(256) void scatter_kernel(const int* __restrict__ esrc,
                                                      const int* __restrict__ edst,
                                                      int* __restrict__ bfill,
                                                      int* __restrict__ slab, int E) {
  __shared__ int cnt[256];
  __shared__ int base[256];
  int t = threadIdx.x;
  int t0 = blockIdx.x * STILE;
  cnt[t] = 0;
  __syncthreads();

  // pass A: histogram
#pragma unroll 4
  for (int i = 0; i < STILE / 1024; ++i) {
    int e = t0 + i * 1024 + t * 4;
    if (e < E) {
      int4 d4 = *(const int4*)(edst + e);
      atomicAdd(&cnt[d4.x >> BSH], 1);
      atomicAdd(&cnt[d4.y >> BSH], 1);
      atomicAdd(&cnt[d4.z >> BSH], 1);
      atomicAdd(&cnt[d4.w >> BSH], 1);
    }
  }
  __syncthreads();
  int c = cnt[t];
  if (c > 0) base[t] = t * BCAP + atomicAdd(&bfill[t], c);
  cnt[t] = 0;
  __syncthreads();

  // pass B: binned write (tile is L2-warm from pass A)
#pragma unroll 4
  for (int i = 0; i < STILE / 1024; ++i) {
    int e = t0 + i * 1024 + t * 4;
    if (e < E) {
      int4 s4 = *(const int4*)(esrc + e);
      int4 d4 = *(const int4*)(edst + e);
#define EMIT(dd, ss)                                             \
      {                                                          \
        int b_ = (dd) >> BSH;                                    \
        int r_ = atomicAdd(&cnt[b_], 1);                         \
        slab[base[b_] + r_] = (((dd) & (BSZ - 1)) << 17) | (ss); \
      }
      EMIT(d4.x, s4.x)
      EMIT(d4.y, s4.y)
      EMIT(d4.z, s4.z)
      EMIT(d4.w, s4.w)
#undef EMIT
    }
  }
}

// ---------------- scan of bucket sizes -> bucket bases ----------------
__global__ __launch_bounds__(256) void bscan_kernel(const int* __restrict__ bfill,
                                                    int* __restrict__ bbase,
                                                    int* __restrict__ row_ptr,
                                                    int nbuck, int N) {
  __shared__ int sh[256];
  int t = threadIdx.x;
  int v = (t < nbuck) ? bfill[t] : 0;
  sh[t] = v;
  __syncthreads();
  for (int off = 1; off < 256; off <<= 1) {
    int u = (t >= off) ? sh[t - off] : 0;
    __syncthreads();
    sh[t] += u;
    __syncthreads();
  }
  if (t < nbuck) bbase[t] = sh[t] - v;  // exclusive
  if (t == 255) {
    bbase[nbuck] = sh[255];
    row_ptr[N] = sh[255];  // == E
  }
}

// ---------------- phase 2: per-bucket CSR finalize ----------------
__global__ __launch_bounds__(256) void build_kernel(const int* __restrict__ slab,
                                                    const int* __restrict__ bfill,
                                                    const int* __restrict__ bbase,
                                                    int* __restrict__ row_ptr,
                                                    float* __restrict__ dinv,
                                                    int* __restrict__ ew, int N) {
  __shared__ int cnt[512];
  __shared__ int pre[512];
  __shared__ int s2[256];
  int b = blockIdx.x;
  int t = threadIdx.x;
  int nbase = b << BSH;
  int nNodes = N - nbase;
  if (nNodes > BSZ) nNodes = BSZ;
  cnt[t] = 0;
  cnt[t + 256] = 0;
  __syncthreads();

  int sz = bfill[b];
  int sbeg = b * BCAP;
  int obase = bbase[b];

  // per-node histogram
  for (int r = t; r < sz; r += 256) atomicAdd(&cnt[((unsigned)slab[sbeg + r]) >> 17], 1);
  __syncthreads();

  // exclusive prefix over 512 counters (pair-sum + 256-wide scan)
  int a = cnt[2 * t], c = cnt[2 * t + 1];
  s2[t] = a + c;
  __syncthreads();
  for (int off = 1; off < 256; off <<= 1) {
    int u = (t >= off) ? s2[t - off] : 0;
    __syncthreads();
    s2[t] += u;
    __syncthreads();
  }
  int ex = s2[t] - (a + c);
  pre[2 * t] = ex;
  pre[2 * t + 1] = ex + a;
  __syncthreads();

  // row_ptr + dinv (coalesced)
  if (t < nNodes) {
    row_ptr[nbase + t] = obase + pre[t];
    dinv[nbase + t] = rsqrtf((float)(cnt[t] + 1));
  }
  int t2 = t + 256;
  if (t2 < nNodes) {
    row_ptr[nbase + t2] = obase + pre[t2];
    dinv[nbase + t2] = rsqrtf((float)(cnt[t2] + 1));
  }
  __syncthreads();
  cnt[t] = 0;
  cnt[t + 256] = 0;
  __syncthreads();

  // final permute: slab (coalesced read, L2-warm) -> node-ordered ew
  for (int r = t; r < sz; r += 256) {
    int rec = slab[sbeg + r];
    int dloc = ((unsigned)rec) >> 17;
    int rank = atomicAdd(&cnt[dloc], 1);
    ew[obase + pre[dloc] + rank] = rec & 0x1FFFF;  // src only; weight folded out
  }
}

// ---------------- dense GEMM with dinv row-scale epilogue ----------------
template <int K, int NC>
__global__ __launch_bounds__(256) void gemm_kernel(const float* __restrict__ A,
                                                   const float* __restrict__ W,
                                                   float* __restrict__ Out,
                                                   const float* __restrict__ rowscale,
                                                   int N) {
  constexpr int BK = 64;
  constexpr int LDSS = 68;           // LDS row stride in floats (17 x float4)
  __shared__ float As[128 * LDSS];   // 34816 B

  int t = threadIdx.x;
  int lane = t & 63;
  int wave = t >> 6;
  int c4 = lane & 15;                // col-quad 0..15
  int qr = lane >> 4;                // row phase 0..3
  int r0 = blockIdx.x * 128;

  int wc = 4 * c4;                   // W col base, clamped in-bounds for NC=40
  if (wc > NC - 4) wc = NC - 4;
  bool cok = (wc == 4 * c4);         // lanes whose cols are real (all for NC=64)

  float4 acc[8];
#pragma unroll
  for (int m = 0; m < 8; ++m) acc[m] = make_float4(0.f, 0.f, 0.f, 0.f);

  for (int kc = 0; kc < K; kc += BK) {
    __syncthreads();  // protect previous chunk's reads
#pragma unroll
    for (int i = 0; i < 8; ++i) {
      int idx = t + i * 256;         // 0..2047
      int row = idx >> 4;            // 0..127
      int cq = idx & 15;
      int gr = r0 + row;
      if (gr >= N) gr = N - 1;
      float4 v = *(const float4*)(A + (size_t)gr * K + kc + 4 * cq);
      *(float4*)(As + row * LDSS + 4 * cq) = v;
    }
    __syncthreads();

#pragma unroll 2
    for (int kk = 0; kk < BK / 4; ++kk) {
      float4 w[4];
#pragma unroll
      for (int k = 0; k < 4; ++k)
        w[k] = *(const float4*)(W + (size_t)(kc + kk * 4 + k) * NC + wc);
#pragma unroll
      for (int m = 0; m < 8; ++m) {
        int lrow = wave * 32 + qr + 4 * m;
        float4 a = *(const float4*)(As + lrow * LDSS + kk * 4);
        acc[m].x = fmaf(a.x, w[0].x, acc[m].x);
        acc[m].y = fmaf(a.x, w[0].y, acc[m].y);
        acc[m].z = fmaf(a.x, w[0].z, acc[m].z);
        acc[m].w = fmaf(a.x, w[0].w, acc[m].w);
        acc[m].x = fmaf(a.y, w[1].x, acc[m].x);
        acc[m].y = fmaf(a.y, w[1].y, acc[m].y);
        acc[m].z = fmaf(a.y, w[1].z, acc[m].z);
        acc[m].w = fmaf(a.y, w[1].w, acc[m].w);
        acc[m].x = fmaf(a.z, w[2].x, acc[m].x);
        acc[m].y = fmaf(a.z, w[2].y, acc[m].y);
        acc[m].z = fmaf(a.z, w[2].z, acc[m].z);
        acc[m].w = fmaf(a.z, w[2].w, acc[m].w);
        acc[m].x = fmaf(a.w, w[3].x, acc[m].x);
        acc[m].y = fmaf(a.w, w[3].y, acc[m].y);
        acc[m].z = fmaf(a.w, w[3].z, acc[m].z);
        acc[m].w = fmaf(a.w, w[3].w, acc[m].w);
      }
    }
  }

  if (cok) {
#pragma unroll
    for (int m = 0; m < 8; ++m) {
      int gr = r0 + wave * 32 + qr + 4 * m;
      if (gr < N) {
        float ds = rowscale[gr];
        acc[m].x *= ds; acc[m].y *= ds; acc[m].z *= ds; acc[m].w *= ds;
        *(float4*)(Out + (size_t)gr * NC + wc) = acc[m];
      }
    }
  }
}

// ---------------- sparse aggregation: one wave per node ----------------
// Round-2 restructure: lanes = 4 edge-slots x 16 feature-quads. One
// global_load_dwordx4 gathers 4 edges x 64B (16B/lane, the coalescing sweet
// spot) vs round-1's one dword (4B/lane) per edge: 4x fewer VMEM instructions,
// 16 edge-gathers in flight per wave (round-1: 4). Epilogue: 8-op shfl_xor
// butterfly (masks 16,32) folds the 4 edge-slots; lanes 0..FQ-1 store float4.
template <int F>
__global__ __launch_bounds__(256) void agg_kernel(const float* __restrict__ Hin,
                                                  const int* __restrict__ row_ptr,
                                                  const int* __restrict__ ew,
                                                  const float* __restrict__ dinv,
                                                  float* __restrict__ Hout, int N) {
  constexpr int FQ = F / 4;          // 16 for F=64, 10 for F=40
  int gid = blockIdx.x * blockDim.x + threadIdx.x;
  int v = gid >> 6;
  if (v >= N) return;
  int lane = threadIdx.x & 63;
  int eg = lane >> 4;                // edge slot 0..3
  int fq = lane & 15;                // feature quad
  bool fok = (fq < FQ);
  int fqc = fok ? fq : 0;

#define GL4(s) (*(const float4*)(Hin + (size_t)(s) * F + fqc * 4))
  float4 acc0, acc1, acc2, acc3;
  acc1 = make_float4(0.f, 0.f, 0.f, 0.f);
  acc2 = acc1;
  acc3 = acc1;
  if (eg == 0) acc0 = GL4(v);        // self-loop term (g_v), counted once
  else acc0 = acc1;

  int beg = __builtin_amdgcn_readfirstlane(row_ptr[v]);
  int end = __builtin_amdgcn_readfirstlane(row_ptr[v + 1]);
  int j = beg;
  for (; j + 16 <= end; j += 16) {
    int s0 = ew[j + eg];
    int s1 = ew[j + 4 + eg];
    int s2 = ew[j + 8 + eg];
    int s3 = ew[j + 12 + eg];
    float4 a = GL4(s0);
    float4 b = GL4(s1);
    float4 c = GL4(s2);
    float4 d = GL4(s3);
    acc0.x += a.x; acc0.y += a.y; acc0.z += a.z; acc0.w += a.w;
    acc1.x += b.x; acc1.y += b.y; acc1.z += b.z; acc1.w += b.w;
    acc2.x += c.x; acc2.y += c.y; acc2.z += c.z; acc2.w += c.w;
    acc3.x += d.x; acc3.y += d.y; acc3.z += d.z; acc3.w += d.w;
  }
  if (j + 8 <= end) {
    int s0 = ew[j + eg];
    int s1 = ew[j + 4 + eg];
    float4 a = GL4(s0);
    float4 b = GL4(s1);
    acc0.x += a.x; acc0.y += a.y; acc0.z += a.z; acc0.w += a.w;
    acc1.x += b.x; acc1.y += b.y; acc1.z += b.z; acc1.w += b.w;
    j += 8;
  }
  {
    int idx = j + eg;
    if (idx < end) {
      float4 a = GL4(ew[idx]);
      acc2.x += a.x; acc2.y += a.y; acc2.z += a.z; acc2.w += a.w;
    }
    idx += 4;
    if (idx < end) {
      float4 a = GL4(ew[idx]);
      acc3.x += a.x; acc3.y += a.y; acc3.z += a.z; acc3.w += a.w;
    }
  }
#undef GL4

  float4 r;
  r.x = (acc0.x + acc1.x) + (acc2.x + acc3.x);
  r.y = (acc0.y + acc1.y) + (acc2.y + acc3.y);
  r.z = (acc0.z + acc1.z) + (acc2.z + acc3.z);
  r.w = (acc0.w + acc1.w) + (acc2.w + acc3.w);
  // fold the 4 edge-slot groups (lanes fq, fq+16, fq+32, fq+48)
  r.x += __shfl_xor(r.x, 16); r.y += __shfl_xor(r.y, 16);
  r.z += __shfl_xor(r.z, 16); r.w += __shfl_xor(r.w, 16);
  r.x += __shfl_xor(r.x, 32); r.y += __shfl_xor(r.y, 32);
  r.z += __shfl_xor(r.z, 32); r.w += __shfl_xor(r.w, 32);

  if (fok && lane < 16) {
    float dv = dinv[v];
    float4 o;
    o.x = fmaxf(dv * r.x, 0.f);
    o.y = fmaxf(dv * r.y, 0.f);
    o.z = fmaxf(dv * r.z, 0.f);
    o.w = fmaxf(dv * r.w, 0.f);
    *(float4*)(Hout + (size_t)v * F + fq * 4) = o;
  }
}

extern "C" void kernel_launch(void* const* d_in, const int* in_sizes, int n_in,
                              void* d_out, int out_size, void* d_ws, size_t ws_size,
                              hipStream_t stream) {
  const float* x  = (const float*)d_in[0];
  const int*   eg = (const int*)d_in[1];
  const float* W0 = (const float*)d_in[2];
  const float* W1 = (const float*)d_in[3];
  const float* W2 = (const float*)d_in[4];
  float* out = (float*)d_out;

  const int N = in_sizes[0] / N_FEAT0;  // 100000
  const int E = in_sizes[1] / 2;        // 1600000
  const int* esrc = eg;
  const int* edst = eg + E;
  const int nbuck = (N + BSZ - 1) >> BSH;  // 196

  // workspace layout (256B aligned)
  char* p = (char*)d_ws;
  auto alloc = [&](size_t bytes) {
    char* r = p;
    p += (bytes + 255) & ~(size_t)255;
    return r;
  };
  int*   bfill   = (int*)alloc(256 * 4);
  int*   bbase   = (int*)alloc(260 * 4);
  int*   row_ptr = (int*)alloc((size_t)(N + 1) * 4);
  float* dinv    = (float*)alloc((size_t)N * 4);
  int*   ew      = (int*)alloc((size_t)E * 4);
  float* bufA    = (float*)alloc((size_t)N * HID * 4);
  float* bufB    = (float*)alloc((size_t)N * HID * 4);
  // per-bucket slab aliases bufA (nbuck*BCAP*4 = 9.6MB <= 25.6MB); build reads
  // it before gemm0 writes bufA (stream-ordered).
  int* slab = (int*)bufA;

  hipMemsetAsync(bfill, 0, 256 * 4, stream);

  const int sblocks = (E + STILE - 1) / STILE;  // 98
  scatter_kernel<<<sblocks, 256, 0, stream>>>(esrc, edst, bfill, slab, E);
  bscan_kernel<<<1, 256, 0, stream>>>(bfill, bbase, row_ptr, nbuck, N);
  build_kernel<<<nbuck, 256, 0, stream>>>(slab, bfill, bbase, row_ptr, dinv, ew, N);

  const int gblocks = (N + 127) / 128;
  const int ablocks = (N + 3) / 4;
  // layer 0: 128 -> 64
  gemm_kernel<128, 64><<<gblocks, 256, 0, stream>>>(x, W0, bufA, dinv, N);
  agg_kernel<64><<<ablocks, 256, 0, stream>>>(bufA, row_ptr, ew, dinv, bufB, N);
  // layer 1: 64 -> 64
  gemm_kernel<64, 64><<<gblocks, 256, 0, stream>>>(bufB, W1, bufA, dinv, N);
  agg_kernel<64><<<ablocks, 256, 0, stream>>>(bufA, row_ptr, ew, dinv, bufB, N);
  // layer 2: 64 -> 40
  gemm_kernel<64, 40><<<gblocks, 256, 0, stream>>>(bufB, W2, bufA, dinv, N);
  agg_kernel<40><<<ablocks, 256, 0, stream>>>(bufA, row_ptr, ew, dinv, out, N);
}

// Round 3
// 338.776 us; speedup vs baseline: 1.4190x; 1.1345x over previous
//
#include <hip/hip_runtime.h>
#include <hip/hip_fp16.h>

#define N_FEAT0 128
#define HID 64
#define NCLS 40

#define BSH 9            // log2 nodes per bucket
#define BSZ 512          // nodes per bucket
#define BCAP 12288       // slab capacity per bucket (mean 8192, sigma ~90 -> 45 sigma margin)
#define STILE 16384      // edges per scatter block

// ---------------- phase 1: LDS-binned scatter of edges into per-bucket slabs ----
// Record = (d & 511) << 17 | s   (s < 2^17 since N = 100000 < 131072).
__global__ __launch_bounds__(256) void scatter_kernel(const int* __restrict__ esrc,
                                                      const int* __restrict__ edst,
                                                      int* __restrict__ bfill,
                                                      int* __restrict__ slab, int E) {
  __shared__ int cnt[256];
  __shared__ int base[256];
  int t = threadIdx.x;
  int t0 = blockIdx.x * STILE;
  cnt[t] = 0;
  __syncthreads();

  // pass A: histogram
#pragma unroll 4
  for (int i = 0; i < STILE / 1024; ++i) {
    int e = t0 + i * 1024 + t * 4;
    if (e < E) {
      int4 d4 = *(const int4*)(edst + e);
      atomicAdd(&cnt[d4.x >> BSH], 1);
      atomicAdd(&cnt[d4.y >> BSH], 1);
      atomicAdd(&cnt[d4.z >> BSH], 1);
      atomicAdd(&cnt[d4.w >> BSH], 1);
    }
  }
  __syncthreads();
  int c = cnt[t];
  if (c > 0) base[t] = t * BCAP + atomicAdd(&bfill[t], c);
  cnt[t] = 0;
  __syncthreads();

  // pass B: binned write (tile is L2-warm from pass A)
#pragma unroll 4
  for (int i = 0; i < STILE / 1024; ++i) {
    int e = t0 + i * 1024 + t * 4;
    if (e < E) {
      int4 s4 = *(const int4*)(esrc + e);
      int4 d4 = *(const int4*)(edst + e);
#define EMIT(dd, ss)                                             \
      {                                                          \
        int b_ = (dd) >> BSH;                                    \
        int r_ = atomicAdd(&cnt[b_], 1);                         \
        slab[base[b_] + r_] = (((dd) & (BSZ - 1)) << 17) | (ss); \
      }
      EMIT(d4.x, s4.x)
      EMIT(d4.y, s4.y)
      EMIT(d4.z, s4.z)
      EMIT(d4.w, s4.w)
#undef EMIT
    }
  }
}

// ---------------- scan of bucket sizes -> bucket bases ----------------
__global__ __launch_bounds__(256) void bscan_kernel(const int* __restrict__ bfill,
                                                    int* __restrict__ bbase,
                                                    int* __restrict__ row_ptr,
                                                    int nbuck, int N) {
  __shared__ int sh[256];
  int t = threadIdx.x;
  int v = (t < nbuck) ? bfill[t] : 0;
  sh[t] = v;
  __syncthreads();
  for (int off = 1; off < 256; off <<= 1) {
    int u = (t >= off) ? sh[t - off] : 0;
    __syncthreads();
    sh[t] += u;
    __syncthreads();
  }
  if (t < nbuck) bbase[t] = sh[t] - v;  // exclusive
  if (t == 255) {
    bbase[nbuck] = sh[255];
    row_ptr[N] = sh[255];  // == E
  }
}

// ---------------- phase 2: per-bucket CSR finalize ----------------
__global__ __launch_bounds__(256) void build_kernel(const int* __restrict__ slab,
                                                    const int* __restrict__ bfill,
                                                    const int* __restrict__ bbase,
                                                    int* __restrict__ row_ptr,
                                                    float* __restrict__ dinv,
                                                    int* __restrict__ ew, int N) {
  __shared__ int cnt[512];
  __shared__ int pre[512];
  __shared__ int s2[256];
  int b = blockIdx.x;
  int t = threadIdx.x;
  int nbase = b << BSH;
  int nNodes = N - nbase;
  if (nNodes > BSZ) nNodes = BSZ;
  cnt[t] = 0;
  cnt[t + 256] = 0;
  __syncthreads();

  int sz = bfill[b];
  int sbeg = b * BCAP;
  int obase = bbase[b];

  // per-node histogram
  for (int r = t; r < sz; r += 256) atomicAdd(&cnt[((unsigned)slab[sbeg + r]) >> 17], 1);
  __syncthreads();

  // exclusive prefix over 512 counters (pair-sum + 256-wide scan)
  int a = cnt[2 * t], c = cnt[2 * t + 1];
  s2[t] = a + c;
  __syncthreads();
  for (int off = 1; off < 256; off <<= 1) {
    int u = (t >= off) ? s2[t - off] : 0;
    __syncthreads();
    s2[t] += u;
    __syncthreads();
  }
  int ex = s2[t] - (a + c);
  pre[2 * t] = ex;
  pre[2 * t + 1] = ex + a;
  __syncthreads();

  // row_ptr + dinv (coalesced)
  if (t < nNodes) {
    row_ptr[nbase + t] = obase + pre[t];
    dinv[nbase + t] = rsqrtf((float)(cnt[t] + 1));
  }
  int t2 = t + 256;
  if (t2 < nNodes) {
    row_ptr[nbase + t2] = obase + pre[t2];
    dinv[nbase + t2] = rsqrtf((float)(cnt[t2] + 1));
  }
  __syncthreads();
  cnt[t] = 0;
  cnt[t + 256] = 0;
  __syncthreads();

  // final permute: slab (coalesced read, L2-warm) -> node-ordered ew
  for (int r = t; r < sz; r += 256) {
    int rec = slab[sbeg + r];
    int dloc = ((unsigned)rec) >> 17;
    int rank = atomicAdd(&cnt[dloc], 1);
    ew[obase + pre[dloc] + rank] = rec & 0x1FFFF;  // src only; weight folded out
  }
}

// ---------------- dense GEMM with dinv row-scale epilogue, fp16 output -------
// G[r][c] = (half) dinv[r] * sum_k A[r][k] W[k][c].  fp16 G halves the random
// gather traffic in agg (the proven fabric-BW wall: round-2 showed duration
// invariant to instruction count at FETCH=190MB / 3.1 TB/s).
template <int K, int NC>
__global__ __launch_bounds__(256) void gemm_kernel(const float* __restrict__ A,
                                                   const float* __restrict__ W,
                                                   __half* __restrict__ Out,
                                                   const float* __restrict__ rowscale,
                                                   int N) {
  constexpr int BK = 64;
  constexpr int LDSS = 68;           // LDS row stride in floats (17 x float4)
  __shared__ float As[128 * LDSS];   // 34816 B

  int t = threadIdx.x;
  int lane = t & 63;
  int wave = t >> 6;
  int c4 = lane & 15;                // col-quad 0..15
  int qr = lane >> 4;                // row phase 0..3
  int r0 = blockIdx.x * 128;

  int wc = 4 * c4;                   // W col base, clamped in-bounds for NC=40
  if (wc > NC - 4) wc = NC - 4;
  bool cok = (wc == 4 * c4);         // lanes whose cols are real (all for NC=64)

  float4 acc[8];
#pragma unroll
  for (int m = 0; m < 8; ++m) acc[m] = make_float4(0.f, 0.f, 0.f, 0.f);

  for (int kc = 0; kc < K; kc += BK) {
    __syncthreads();  // protect previous chunk's reads
#pragma unroll
    for (int i = 0; i < 8; ++i) {
      int idx = t + i * 256;         // 0..2047
      int row = idx >> 4;            // 0..127
      int cq = idx & 15;
      int gr = r0 + row;
      if (gr >= N) gr = N - 1;
      float4 v = *(const float4*)(A + (size_t)gr * K + kc + 4 * cq);
      *(float4*)(As + row * LDSS + 4 * cq) = v;
    }
    __syncthreads();

#pragma unroll 2
    for (int kk = 0; kk < BK / 4; ++kk) {
      float4 w[4];
#pragma unroll
      for (int k = 0; k < 4; ++k)
        w[k] = *(const float4*)(W + (size_t)(kc + kk * 4 + k) * NC + wc);
#pragma unroll
      for (int m = 0; m < 8; ++m) {
        int lrow = wave * 32 + qr + 4 * m;
        float4 a = *(const float4*)(As + lrow * LDSS + kk * 4);
        acc[m].x = fmaf(a.x, w[0].x, acc[m].x);
        acc[m].y = fmaf(a.x, w[0].y, acc[m].y);
        acc[m].z = fmaf(a.x, w[0].z, acc[m].z);
        acc[m].w = fmaf(a.x, w[0].w, acc[m].w);
        acc[m].x = fmaf(a.y, w[1].x, acc[m].x);
        acc[m].y = fmaf(a.y, w[1].y, acc[m].y);
        acc[m].z = fmaf(a.y, w[1].z, acc[m].z);
        acc[m].w = fmaf(a.y, w[1].w, acc[m].w);
        acc[m].x = fmaf(a.z, w[2].x, acc[m].x);
        acc[m].y = fmaf(a.z, w[2].y, acc[m].y);
        acc[m].z = fmaf(a.z, w[2].z, acc[m].z);
        acc[m].w = fmaf(a.z, w[2].w, acc[m].w);
        acc[m].x = fmaf(a.w, w[3].x, acc[m].x);
        acc[m].y = fmaf(a.w, w[3].y, acc[m].y);
        acc[m].z = fmaf(a.w, w[3].z, acc[m].z);
        acc[m].w = fmaf(a.w, w[3].w, acc[m].w);
      }
    }
  }

  if (cok) {
#pragma unroll
    for (int m = 0; m < 8; ++m) {
      int gr = r0 + wave * 32 + qr + 4 * m;
      if (gr < N) {
        float ds = rowscale[gr];
        union { __half2 h[2]; uint2 u; } cv;
        cv.h[0] = __floats2half2_rn(ds * acc[m].x, ds * acc[m].y);
        cv.h[1] = __floats2half2_rn(ds * acc[m].z, ds * acc[m].w);
        *(uint2*)(Out + (size_t)gr * NC + wc) = cv.u;
      }
    }
  }
}

// ---------------- sparse aggregation: one wave per node, fp16 gather ---------
// Lanes = 8 edge-slots x 8 feature-octs. F=64 fp16 row = 128 B = ONE cache
// line; one dwordx4 gathers 8 full rows (1 KB). f32 accumulate, 3-level
// shfl_xor fold (masks 8/16/32), f32 output.
template <int F>
__global__ __launch_bounds__(256) void agg_kernel(const __half* __restrict__ G,
                                                  const int* __restrict__ row_ptr,
                                                  const int* __restrict__ ew,
                                                  const float* __restrict__ dinv,
                                                  float* __restrict__ Hout, int N) {
  constexpr int FO = F / 8;          // feature octs: 8 for F=64, 5 for F=40
  int gid = blockIdx.x * blockDim.x + threadIdx.x;
  int v = gid >> 6;
  if (v >= N) return;
  int lane = threadIdx.x & 63;
  int eg = lane >> 3;                // edge slot 0..7
  int fo = lane & 7;                 // feature oct
  bool fok = (fo < FO);
  int foc = fok ? fo : FO - 1;       // clamped lanes fold only among themselves

  float acc[8];
#pragma unroll
  for (int i = 0; i < 8; ++i) acc[i] = 0.f;

#define GLD(s) (*(const uint4*)(G + (size_t)(s) * F + foc * 8))
  auto addrow = [&](uint4 q) {
    const __half2* h = (const __half2*)&q;
#pragma unroll
    for (int i = 0; i < 4; ++i) {
      float2 f = __half22float2(h[i]);
      acc[2 * i] += f.x;
      acc[2 * i + 1] += f.y;
    }
  };

  if (eg == 0) addrow(GLD(v));       // self-loop term (g_v), counted once

  int beg = __builtin_amdgcn_readfirstlane(row_ptr[v]);
  int end = __builtin_amdgcn_readfirstlane(row_ptr[v + 1]);
  int j = beg;
  for (; j + 16 <= end; j += 16) {
    int s0 = ew[j + eg];
    int s1 = ew[j + 8 + eg];
    uint4 a = GLD(s0);
    uint4 b = GLD(s1);
    addrow(a);
    addrow(b);
  }
  if (j + 8 <= end) {
    addrow(GLD(ew[j + eg]));
    j += 8;
  }
  {
    int idx = j + eg;
    if (idx < end) addrow(GLD(ew[idx]));
  }
#undef GLD

  // fold the 8 edge-slot groups (lane bits 3..5)
#pragma unroll
  for (int m = 8; m <= 32; m <<= 1) {
#pragma unroll
    for (int i = 0; i < 8; ++i) acc[i] += __shfl_xor(acc[i], m);
  }

  if (fok) {
    float dv = dinv[v];
    float4 o0, o1;
    o0.x = fmaxf(dv * acc[0], 0.f);
    o0.y = fmaxf(dv * acc[1], 0.f);
    o0.z = fmaxf(dv * acc[2], 0.f);
    o0.w = fmaxf(dv * acc[3], 0.f);
    o1.x = fmaxf(dv * acc[4], 0.f);
    o1.y = fmaxf(dv * acc[5], 0.f);
    o1.z = fmaxf(dv * acc[6], 0.f);
    o1.w = fmaxf(dv * acc[7], 0.f);
    float4* outp = (float4*)(Hout + (size_t)v * F + fo * 8);
    outp[0] = o0;
    outp[1] = o1;
  }
}

extern "C" void kernel_launch(void* const* d_in, const int* in_sizes, int n_in,
                              void* d_out, int out_size, void* d_ws, size_t ws_size,
                              hipStream_t stream) {
  const float* x  = (const float*)d_in[0];
  const int*   eg = (const int*)d_in[1];
  const float* W0 = (const float*)d_in[2];
  const float* W1 = (const float*)d_in[3];
  const float* W2 = (const float*)d_in[4];
  float* out = (float*)d_out;

  const int N = in_sizes[0] / N_FEAT0;  // 100000
  const int E = in_sizes[1] / 2;        // 1600000
  const int* esrc = eg;
  const int* edst = eg + E;
  const int nbuck = (N + BSZ - 1) >> BSH;  // 196

  // workspace layout (256B aligned)
  char* p = (char*)d_ws;
  auto alloc = [&](size_t bytes) {
    char* r = p;
    p += (bytes + 255) & ~(size_t)255;
    return r;
  };
  int*    bfill   = (int*)alloc(256 * 4);
  int*    bbase   = (int*)alloc(260 * 4);
  int*    row_ptr = (int*)alloc((size_t)(N + 1) * 4);
  float*  dinv    = (float*)alloc((size_t)N * 4);
  int*    ew      = (int*)alloc((size_t)E * 4);
  __half* bufG    = (__half*)alloc((size_t)N * HID * 2);  // fp16 messages
  float*  bufH    = (float*)alloc((size_t)N * HID * 4);   // f32 hidden
  // per-bucket slab aliases bufH (nbuck*BCAP*4 = 9.6MB <= 25.6MB); build reads
  // it before agg0 writes bufH (stream-ordered).
  int* slab = (int*)bufH;

  hipMemsetAsync(bfill, 0, 256 * 4, stream);

  const int sblocks = (E + STILE - 1) / STILE;  // 98
  scatter_kernel<<<sblocks, 256, 0, stream>>>(esrc, edst, bfill, slab, E);
  bscan_kernel<<<1, 256, 0, stream>>>(bfill, bbase, row_ptr, nbuck, N);
  build_kernel<<<nbuck, 256, 0, stream>>>(slab, bfill, bbase, row_ptr, dinv, ew, N);

  const int gblocks = (N + 127) / 128;
  const int ablocks = (N + 3) / 4;
  // layer 0: 128 -> 64
  gemm_kernel<128, 64><<<gblocks, 256, 0, stream>>>(x, W0, bufG, dinv, N);
  agg_kernel<64><<<ablocks, 256, 0, stream>>>(bufG, row_ptr, ew, dinv, bufH, N);
  // layer 1: 64 -> 64
  gemm_kernel<64, 64><<<gblocks, 256, 0, stream>>>(bufH, W1, bufG, dinv, N);
  agg_kernel<64><<<ablocks, 256, 0, stream>>>(bufG, row_ptr, ew, dinv, bufH, N);
  // layer 2: 64 -> 40
  gemm_kernel<64, 40><<<gblocks, 256, 0, stream>>>(bufH, W2, bufG, dinv, N);
  agg_kernel<40><<<ablocks, 256, 0, stream>>>(bufG, row_ptr, ew, dinv, out, N);
}